// Round 13
// baseline (233.192 us; speedup 1.0000x reference)
//
#include <hip/hip_runtime.h>
#include <math.h>

#define S 1024
#define E 1024
#define H 32
#define KSEL 8
#define D 128
#define HD 4096      // H*D
#define SK 8192      // S*KSEL
#define MAXL 1024
#define CAP 9216     // SK + H*31 padding (per-head padded to 32)
#define ATTN_SCALE 0.08838834764831845f  // 1/sqrt(128)
#define SSTR 36
#define PSTR 40

#define NROUTERB 1024        // one block per token (4-wave cooperative)
#define NCONV 832            // 3*(8*32) + 8*8 transpose tiles (128x128)
#define NTAB 512             // rope-table builder blocks

typedef _Float16 half8 __attribute__((ext_vector_type(8)));
typedef _Float16 half4 __attribute__((ext_vector_type(4)));
typedef float floatx16 __attribute__((ext_vector_type(16)));
typedef float f4 __attribute__((ext_vector_type(4)));

// async 16B global -> LDS (lands at wave-uniform base + lane*16)
#define GLOAD_LDS16(gsrc, ldst) \
    __builtin_amdgcn_global_load_lds( \
        (const __attribute__((address_space(1))) void*)(gsrc), \
        (__attribute__((address_space(3))) void*)(ldst), 16, 0, 0)

// ---- tiled Q/K layout: element (slot, d) of a head lives at
//   (hb + (slot&~31))*D + ((d>>3)*32 + (slot&31))*8 + (d&7)
// ---- tiled V layout: element (col, slot) at
//   (hb + (slot&~31))*D + (((slot&31)>>3)*128 + col)*8 + (slot&7)
// NOTE (round-8): device-scope fences / acquire-polling inside a BW-bound dispatch
// collapse its bandwidth 6x on gfx950 — keep scan as its own launch.
// NOTE (round-9): every global store needs exactly one owner (Wot race => absmax 20x).
// NOTE (round-10/11): XCD = linear_block_id % 8. Blocks sharing an operand panel must
// be ≡ mod 8 (same XCD L2). Round-13: ALSO cluster sharers in that XCD's dispatch
// sequence (ids 8 apart, consecutive) so they're co-resident -> HBM dedup, not just L2.
// Round-13: conv blocks first in dispatch-1 (BW-bound saturates immediately); routers
// last (latency tail hides under conv).

// wave-parallel per-head prefix: 1 coalesced load + 5 shfl (vs 31 serial loads).
__device__ __forceinline__ void head_prefix(const int* __restrict__ hlen, int h,
                                            int lane, int& len, int& hb, int& lenp)
{
    int hl = (lane < 32) ? hlen[lane] : 0;
    int hp = (hl + 31) & ~31;
    int pref = hp;
    #pragma unroll
    for (int off = 1; off < 32; off <<= 1) {
        int t = __shfl_up(pref, off, 64);
        if (lane >= off) pref += t;
    }
    int excl = pref - hp;
    hb   = __shfl(excl, h, 64);
    len  = __shfl(hl, h, 64);
    lenp = (len + 31) & ~31;
}

// ---------------- merged dispatch 1: conv (first) + rope table + routers (last) ----
__global__ __launch_bounds__(256) void router_conv_kernel(
    const float* __restrict__ x, const float* __restrict__ Wr,
    int* __restrict__ head_idx, float* __restrict__ head_w,
    float* __restrict__ pbuf, float* __restrict__ entz,
    _Float16* __restrict__ xh,
    const float* __restrict__ Wq, const float* __restrict__ Wk,
    const float* __restrict__ Wv, const float* __restrict__ Wo,
    _Float16* __restrict__ Wqkt, _Float16* __restrict__ Wot,
    float2* __restrict__ tab)
{
    int bid = blockIdx.x, tid = threadIdx.x;
    __shared__ __align__(16) char smem[128 * 128 * 2];   // union: conv tile / router partials
    if (bid < NCONV) {
        // ---- 128x128 weight transpose+convert (single owner per output chunk) ----
        _Float16* tl = (_Float16*)smem;
        int cb = bid;
        int z, rem;
        if (cb < 768) { z = cb >> 8; rem = cb & 255; }
        else          { z = 3;       rem = cb - 768; }
        const float* W = (z == 0) ? Wq : (z == 1) ? Wk : (z == 2) ? Wv : Wo;
        _Float16* T = (z < 3) ? (Wqkt + (size_t)z * HD * E) : Wot;
        int C = (z < 3) ? HD : 1024;
        int nc = C >> 7;
        int c0 = (rem % nc) * 128;
        int r0 = (rem / nc) * 128;
        #pragma unroll
        for (int p = 0; p < 16; ++p) {
            int idx = p * 256 + tid;
            int rr = idx >> 5, cg = (idx & 31) * 4;
            f4 v = *(const f4*)&W[(size_t)(r0 + rr) * C + c0 + cg];
            half4 o;
            o.x = (_Float16)v.x; o.y = (_Float16)v.y;
            o.z = (_Float16)v.z; o.w = (_Float16)v.w;
            int sc = cg ^ (((rr >> 3) & 7) << 2);
            *(half4*)&tl[rr * 128 + sc] = o;
        }
        __syncthreads();
        #pragma unroll
        for (int p = 0; p < 8; ++p) {
            int chunk = p * 256 + tid;
            int cc = chunk >> 4, ch = chunk & 15;
            int cidx = cc ^ ((ch & 7) << 2);
            half8 o;
            #pragma unroll
            for (int j = 0; j < 8; ++j)
                o[j] = tl[(ch * 8 + j) * 128 + cidx];
            *(half8*)&T[(size_t)(c0 + cc) * 1024 + r0 + ch * 8] = o;
        }
        return;
    }
    if (bid < NCONV + NTAB) {
        // ---- rope table: tab[p*64+d2] = {cos, sin}(p * 10000^(-d2/64)) ----
        int base = (bid - NCONV) * 1024;
        #pragma unroll
        for (int j = 0; j < 4; ++j) {
            int idx = base + j * 256 + tid;
            int p = idx >> 6, d2 = idx & 63;
            float inv = exp2f((float)d2 * -0.20762050f);
            float ang = (float)p * inv;
            float sn, cs;
            sincosf(ang, &sn, &cs);
            tab[idx] = make_float2(cs, sn);
        }
        return;
    }
    // ---- router: ONE token per block; 4 waves split E into 8x128 segments ----
    int s = bid - NCONV - NTAB;
    int w = tid >> 6, lane = tid & 63;
    int h = lane & 31;
    int seg = w * 2 + (lane >> 5);          // 0..7
    float* partial = (float*)smem;          // [4][32]
    const float* xr = x + (size_t)s * E + seg * 128;
    const float* wr = Wr + (size_t)(seg * 128) * H + h;
    float a0 = 0.f, a1 = 0.f, a2 = 0.f, a3 = 0.f;
    #pragma unroll 4
    for (int e = 0; e < 128; e += 4) {
        a0 += xr[e]     * wr[e * H];
        a1 += xr[e + 1] * wr[(e + 1) * H];
        a2 += xr[e + 2] * wr[(e + 2) * H];
        a3 += xr[e + 3] * wr[(e + 3) * H];
    }
    float acc = (a0 + a1) + (a2 + a3);
    acc += __shfl_xor(acc, 32, 64);         // combine the wave's two segments
    if (lane < 32) partial[w * 32 + h] = acc;
    __syncthreads();
    float logit = partial[h] + partial[32 + h] + partial[64 + h] + partial[96 + h];
    if (w == 0) {
        float m = logit;
        #pragma unroll
        for (int off = 16; off; off >>= 1) m = fmaxf(m, __shfl_xor(m, off, 64));
        float ex = expf(logit - m);
        float Z = ex;
        #pragma unroll
        for (int off = 16; off; off >>= 1) Z += __shfl_xor(Z, off, 64);
        float p = ex / Z;
        float es = p * logf(p + 1e-8f);
        #pragma unroll
        for (int off = 16; off; off >>= 1) es += __shfl_xor(es, off, 64);
        float lse = m + logf(Z);
        float lv = logit;
        float tv[KSEL]; int ti[KSEL];
        #pragma unroll
        for (int j = 0; j < KSEL; ++j) {
            float bv = lv; int bi = h;
            #pragma unroll
            for (int off = 16; off; off >>= 1) {
                float ov = __shfl_xor(bv, off, 64);
                int oi = __shfl_xor(bi, off, 64);
                if (ov > bv || (ov == bv && oi < bi)) { bv = ov; bi = oi; }
            }
            tv[j] = bv; ti[j] = bi;
            if (h == bi) lv = -INFINITY;
        }
        float Z2 = 0.f;
        #pragma unroll
        for (int j = 0; j < KSEL; ++j) Z2 += expf(tv[j] - tv[0]);
        if (lane < 32) pbuf[s * 32 + lane] = p;
        if (lane == 0) {
            entz[s * 2]     = es;
            entz[s * 2 + 1] = lse * lse;
            #pragma unroll
            for (int j = 0; j < KSEL; ++j) {
                head_idx[s * KSEL + j] = ti[j];
                head_w[s * KSEL + j]   = expf(tv[j] - tv[0]) / Z2;
            }
        }
    }
    // fused x -> fp16: 256 threads x 4 elements, coalesced
    {
        int e = tid * 4;
        f4 v = *(const f4*)&x[(size_t)s * E + e];
        half4 o;
        o.x = (_Float16)v.x; o.y = (_Float16)v.y; o.z = (_Float16)v.z; o.w = (_Float16)v.w;
        *(half4*)&xh[(size_t)s * E + e] = o;
    }
}

// ---------------- scan (blocks 0..31, 2048/iter) + aux (block 32): separate launch ----
__global__ __launch_bounds__(256) void scan_aux_kernel(
    const int* __restrict__ head_idx, const int* __restrict__ head_counts,
    int* __restrict__ order, int* __restrict__ hlen, float* __restrict__ out_counts,
    const float* __restrict__ pbuf, const float* __restrict__ entz,
    float* __restrict__ out_aux)
{
    int bid = blockIdx.x, tid = threadIdx.x;
    if (bid == H) {
        int hh = tid & 31, grp = tid >> 5;
        __shared__ float red[256], red2[256];
        __shared__ float psum[32];
        __shared__ int hist[32];
        if (tid < 32) hist[tid] = 0;
        float ps = 0.f;
        for (int s = grp; s < S; s += 8) ps += pbuf[s * 32 + hh];
        red[tid] = ps;
        float es = 0.f, zs = 0.f;
        for (int s = tid; s < S; s += 256) { es += entz[s * 2]; zs += entz[s * 2 + 1]; }
        red2[tid] = es;
        __syncthreads();
        if (grp == 0) {
            float v = 0.f;
            #pragma unroll
            for (int j = 0; j < 8; ++j) v += red[j * 32 + hh];
            psum[hh] = v;
        }
        __syncthreads();
        red[tid] = zs;
        for (int s = tid; s < S; s += 256)
            atomicAdd(&hist[head_idx[s * KSEL]], 1);
        __syncthreads();
        for (int stp = 128; stp; stp >>= 1) {
            if (tid < stp) { red[tid] += red[tid + stp]; red2[tid] += red2[tid + stp]; }
            __syncthreads();
        }
        if (tid == 0) {
            float bal = 0.f;
            for (int j = 0; j < H; ++j)
                bal += ((float)hist[j] / (float)S) * (psum[j] / (float)S);
            bal *= (float)H;
            float ent_loss = red2[0] / (float)S;
            float z = red[0] / (float)S * 0.01f;
            out_aux[0] = 0.01f * bal + 0.01f * ent_loss + z;
        }
        return;
    }
    int h = bid;
    int wave = tid >> 6, lane = tid & 63;
    __shared__ int wtot[8][4];
    int base = 0;
    int hc = head_counts[h];
    int v[8], n[8];
    #pragma unroll
    for (int j = 0; j < 8; ++j) v[j] = head_idx[j * 256 + tid];
    unsigned long long lt = (1ull << lane) - 1ull;
    for (int c0 = 0; c0 < SK; c0 += 2048) {
        #pragma unroll
        for (int j = 0; j < 8; ++j)
            n[j] = (c0 + 2048 < SK) ? head_idx[c0 + 2048 + j * 256 + tid] : 0;
        bool p[8];
        int wi[8];
        #pragma unroll
        for (int j = 0; j < 8; ++j) {
            p[j] = (v[j] == h);
            unsigned long long m = __ballot(p[j]);
            wi[j] = __popcll(m & lt);
            if (lane == 0) wtot[j][wave] = __popcll(m);
        }
        __syncthreads();
        int pre[8], T[8];
        #pragma unroll
        for (int i = 0; i < 8; ++i) {
            int pr = 0, tot = 0;
            #pragma unroll
            for (int w = 0; w < 4; ++w) {
                int tv = wtot[i][w];
                if (w < wave) pr += tv;
                tot += tv;
            }
            pre[i] = pr; T[i] = tot;
        }
        int run = base;
        #pragma unroll
        for (int j = 0; j < 8; ++j) {
            if (p[j]) order[h * MAXL + run + pre[j] + wi[j]] = c0 + j * 256 + tid;
            run += T[j];
        }
        base = run;
        __syncthreads();
        #pragma unroll
        for (int j = 0; j < 8; ++j) v[j] = n[j];
    }
    if (tid == 0) {
        hlen[h] = base;
        out_counts[h] = (float)(hc + base);
    }
}

// ---------------- gathered QKV projection: B-only LDS dbuf, A direct-to-reg + fused RoPE
// 1D grid 1536, XCD-affine rt-clustering: bid = xcd + 8*(rt + 16*(xid/8)).
// All 16 rt-blocks of one (proj,head) panel are CONSECUTIVE in their XCD's dispatch
// sequence -> co-resident -> panel fetched from HBM once, 15x from L2.
__global__ __launch_bounds__(256) void qkv_mfma(
    const _Float16* __restrict__ xh, const _Float16* __restrict__ Wt,
    const int* __restrict__ order, const int* __restrict__ hlen,
    const int* __restrict__ head_counts, const float2* __restrict__ tab,
    _Float16* __restrict__ qh, _Float16* __restrict__ kh, _Float16* __restrict__ vT)
{
    int bid = blockIdx.x;
    int xcd = bid & 7;
    int slot = bid >> 3;
    int rt = slot & 15;
    int xid = xcd + 8 * (slot >> 4);     // 0..95
    int qkv = xid >> 5, h = xid & 31;
    int tid = threadIdx.x, wave = tid >> 6, lane = tid & 63;
    int len, hb, lenp;
    head_prefix(hlen, h, lane, len, hb, lenp);
    int row0 = rt * 64;
    if (row0 >= len) return;
    int wm = wave >> 1, wn = wave & 1;
    int l32 = lane & 31, g = lane >> 5;

    __shared__ _Float16 Bs[2][128 * 64];

    int arow_g = row0 + wm * 32 + l32;
    int tok = (arow_g < len) ? (order[h * MAXL + arow_g] >> 3) : 0;
    const _Float16* aptr = xh + (size_t)tok * E;
    const _Float16* Wb = Wt + (size_t)((qkv * H + h) * D) * E;

    auto stageB = [&](int buf, int k0) {
        #pragma unroll
        for (int it = 0; it < 4; ++it) {
            int f = it * 256 + tid;
            int row = f >> 3, c = f & 7;
            int sc = c ^ (row & 7);
            const _Float16* src = Wb + (size_t)row * E + k0 + sc * 8;
            GLOAD_LDS16(src, &Bs[buf][f * 8]);
        }
    };

    floatx16 acc[2] = {};
    half8 a_cur[4], a_nxt[4];
    #pragma unroll
    for (int ks = 0; ks < 4; ++ks)
        a_cur[ks] = *(const half8*)(aptr + ks * 16 + g * 8);

    auto compute = [&](int buf, half8* a) {
        #pragma unroll
        for (int ks = 0; ks < 4; ++ks) {
            int wchunk = ks * 2 + g;
            #pragma unroll
            for (int nf = 0; nf < 2; ++nf) {
                int brow = wn * 64 + nf * 32 + l32;
                half8 bf = *(const half8*)&Bs[buf][brow * 64 + (wchunk ^ (brow & 7)) * 8];
                acc[nf] = __builtin_amdgcn_mfma_f32_32x32x16_f16(a[ks], bf, acc[nf], 0, 0, 0);
            }
        }
    };

    stageB(0, 0);
    __syncthreads();
    int buf = 0;
    for (int k0 = 64; k0 < E; k0 += 64) {
        stageB(buf ^ 1, k0);
        #pragma unroll
        for (int ks = 0; ks < 4; ++ks)
            a_nxt[ks] = *(const half8*)(aptr + k0 + ks * 16 + g * 8);
        compute(buf, a_cur);
        __syncthreads();
        buf ^= 1;
        #pragma unroll
        for (int ks = 0; ks < 4; ++ks) a_cur[ks] = a_nxt[ks];
    }
    compute(buf, a_cur);

    if (qkv < 2) {
        // fused RoPE -> TILED write, vectorized: 2 passes, half8 stores.
        _Float16* dst = (qkv == 0) ? qh : kh;
        float* scr = (float*)&Bs[0][0];
        __syncthreads();
        #pragma unroll
        for (int nf = 0; nf < 2; ++nf) {
            int col = wn * 64 + nf * 32 + l32;
            #pragma unroll
            for (int reg = 0; reg < 16; ++reg) {
                int rl = wm * 32 + (reg & 3) + 8 * (reg >> 2) + 4 * g;
                scr[rl * 128 + col] = acc[nf][reg];
            }
        }
        __syncthreads();
        int hc = head_counts[h];
        #pragma unroll
        for (int pass = 0; pass < 2; ++pass) {
            int item = pass * 256 + tid;
            int r = item >> 3;          // local slot 0..63
            int c0 = item & 7;          // k-chunk
            int slot2 = row0 + r;
            if (slot2 < len) {
                int p = slot2 + hc;
                p = p < 0 ? 0 : (p > 8191 ? 8191 : p);
                float vv1[8], vv2[8];
                *(f4*)(vv1)     = *(const f4*)&scr[r * 128 + c0 * 8];
                *(f4*)(vv1 + 4) = *(const f4*)&scr[r * 128 + c0 * 8 + 4];
                *(f4*)(vv2)     = *(const f4*)&scr[r * 128 + 64 + c0 * 8];
                *(f4*)(vv2 + 4) = *(const f4*)&scr[r * 128 + 64 + c0 * 8 + 4];
                half8 o1, o2;
                #pragma unroll
                for (int j = 0; j < 8; ++j) {
                    float2 tt = tab[p * 64 + c0 * 8 + j];
                    o1[j] = (_Float16)(vv1[j] * tt.x - vv2[j] * tt.y);
                    o2[j] = (_Float16)(vv2[j] * tt.x + vv1[j] * tt.y);
                }
                size_t tb = (size_t)(hb + (slot2 & ~31)) * D;
                int sl5 = slot2 & 31;
                *(half8*)&dst[tb + (size_t)(c0 * 32 + sl5) * 8]       = o1;
                *(half8*)&dst[tb + (size_t)((c0 + 8) * 32 + sl5) * 8] = o2;
            }
        }
    } else {
        // TILED V write: (col,slot) -> (hb+(slot&~31))*D + (((slot&31)>>3)*128+col)*8 + (slot&7)
        #pragma unroll
        for (int nf = 0; nf < 2; ++nf) {
            int col = wn * 64 + nf * 32 + l32;
            #pragma unroll
            for (int q4 = 0; q4 < 4; ++q4) {
                int slot0 = row0 + wm * 32 + 8 * q4 + 4 * g;
                size_t tb = (size_t)(hb + (slot0 & ~31)) * D;
                int sc = (slot0 & 31) >> 3;
                _Float16* vp = vT + tb + (size_t)(sc * 128 + col) * 8 + (slot0 & 7);
                if (slot0 + 3 < len) {
                    half4 o;
                    o.x = (_Float16)acc[nf][q4 * 4 + 0];
                    o.y = (_Float16)acc[nf][q4 * 4 + 1];
                    o.z = (_Float16)acc[nf][q4 * 4 + 2];
                    o.w = (_Float16)acc[nf][q4 * 4 + 3];
                    *(half4*)vp = o;
                } else {
                    #pragma unroll
                    for (int r2 = 0; r2 < 4; ++r2) {
                        int sl = slot0 + r2;
                        if (sl < len) vp[r2] = (_Float16)acc[nf][q4 * 4 + r2];
                        else if (sl < lenp) vp[r2] = (_Float16)0.f;   // keep pad NaN-free
                    }
                }
            }
        }
    }
}

// ---------------- per-head causal flash attention: tiled dense loads.
// h = bid&31 (XCD = h%8: per-head K/V stays in one XCD's L2), qt = 31-(bid>>5).
__global__ __launch_bounds__(128) void attn_mfma(
    const _Float16* __restrict__ qh, const _Float16* __restrict__ kh,
    const _Float16* __restrict__ vT,
    const int* __restrict__ order, const int* __restrict__ hlen,
    const float* __restrict__ head_w, _Float16* __restrict__ ao)
{
    int h = blockIdx.x & 31;
    int qt = 31 - (int)(blockIdx.x >> 5);
    int tid = threadIdx.x;
    int w = tid >> 6, lane = tid & 63;
    int len, hb, lenp;
    head_prefix(hlen, h, lane, len, hb, lenp);
    int row0 = qt * 32;
    if (row0 >= len) return;
    int l32 = lane & 31, g = lane >> 5;
    int srow = lane >> 1, shalf = lane & 1;

    __shared__ float Sld[2][32 * SSTR];
    __shared__ _Float16 Pld[2][32 * PSTR];
    __shared__ float alphaLd[2][32];
    __shared__ float mlLd[32][4];     // m0,l0,m1,l1
    __shared__ float facLd[32][3];    // f1, hw/l*, f0
    __shared__ int flatLd[32];
    __shared__ float Obuf[32][128];

    if (tid < 32) {
        int r = row0 + tid;
        flatLd[tid] = (r < len) ? order[h * MAXL + r] : -1;
    }

    // dense tiled Q load: 1KB contiguous per wave-chunk
    const _Float16* qtile = qh + (size_t)(hb + row0) * D;
    half8 qf[8];
    #pragma unroll
    for (int t = 0; t < 8; ++t)
        qf[t] = *(const half8*)(qtile + (size_t)((t * 2 + g) * 32 + l32) * 8);

    floatx16 O[4] = {};
    float m_run = -INFINITY, l_run = 0.f;

    if (w <= qt) {
        half8 kf[8], kfn[8], vv[8];
        {
            const _Float16* ktile = kh + (size_t)(hb + w * 32) * D;
            #pragma unroll
            for (int t = 0; t < 8; ++t)
                kf[t] = *(const half8*)(ktile + (size_t)((t * 2 + g) * 32 + l32) * 8);
        }
        for (int kt = w; kt <= qt; kt += 2) {
            int col0 = kt * 32;
            floatx16 Sc = {};
            #pragma unroll
            for (int t = 0; t < 8; ++t)
                Sc = __builtin_amdgcn_mfma_f32_32x32x16_f16(qf[t], kf[t], Sc, 0, 0, 0);
            // dense tiled V load for this kt tile
            {
                const _Float16* vtile = vT + (size_t)(hb + col0) * D;
                #pragma unroll
                for (int nt = 0; nt < 4; ++nt) {
                    vv[nt * 2]     = *(const half8*)(vtile + (size_t)(g * 128 + nt * 32 + l32) * 8);
                    vv[nt * 2 + 1] = *(const half8*)(vtile + (size_t)((2 + g) * 128 + nt * 32 + l32) * 8);
                }
            }
            if (kt + 2 <= qt) {
                const _Float16* ktile = kh + (size_t)(hb + col0 + 64) * D;
                #pragma unroll
                for (int t = 0; t < 8; ++t)
                    kfn[t] = *(const half8*)(ktile + (size_t)((t * 2 + g) * 32 + l32) * 8);
            }
            bool diag = (kt == qt);
            #pragma unroll
            for (int reg = 0; reg < 16; ++reg) {
                int row = (reg & 3) + 8 * (reg >> 2) + 4 * g;
                float s = Sc[reg] * ATTN_SCALE;
                if (diag && l32 > row) s = -1e30f;
                Sld[w][row * SSTR + l32] = s;
            }
            __builtin_amdgcn_wave_barrier();
            const float* sp = &Sld[w][srow * SSTR + shalf * 16];
            float va[16];
            *(f4*)(va)      = *(const f4*)(sp);
            *(f4*)(va + 4)  = *(const f4*)(sp + 4);
            *(f4*)(va + 8)  = *(const f4*)(sp + 8);
            *(f4*)(va + 12) = *(const f4*)(sp + 12);
            float mt_ = va[0];
            #pragma unroll
            for (int j = 1; j < 16; ++j) mt_ = fmaxf(mt_, va[j]);
            mt_ = fmaxf(mt_, __shfl_xor(mt_, 1, 64));
            float m_new = fmaxf(m_run, mt_);
            float alpha = __expf(m_run - m_new);
            float p[16], tsum = 0.f;
            #pragma unroll
            for (int j = 0; j < 16; ++j) { p[j] = __expf(va[j] - m_new); tsum += p[j]; }
            tsum += __shfl_xor(tsum, 1, 64);
            l_run = l_run * alpha + tsum;
            m_run = m_new;
            half8 ph0, ph1;
            #pragma unroll
            for (int j = 0; j < 8; ++j) { ph0[j] = (_Float16)p[j]; ph1[j] = (_Float16)p[j + 8]; }
            *(half8*)&Pld[w][srow * PSTR + shalf * 16]     = ph0;
            *(half8*)&Pld[w][srow * PSTR + shalf * 16 + 8] = ph1;
            if (shalf == 0) alphaLd[w][srow] = alpha;
            __builtin_amdgcn_wave_barrier();
            f4 al[4];
            #pragma unroll
            for (int qq = 0; qq < 4; ++qq) al[qq] = *(const f4*)&alphaLd[w][4 * g + 8 * qq];
            #pragma unroll
            for (int reg = 0; reg < 16; ++reg) {
                float av = al[reg >> 2][reg & 3];
                O[0][reg] *= av; O[1][reg] *= av; O[2][reg] *= av; O[3][reg] *= av;
            }
            half8 pf0 = *(const half8*)&Pld[w][l32 * PSTR + g * 8];
            half8 pf1 = *(const half8*)&Pld[w][l32 * PSTR + 16 + g * 8];
            #pragma unroll
            for (int nt = 0; nt < 4; ++nt) {
                O[nt] = __builtin_amdgcn_mfma_f32_32x32x16_f16(pf0, vv[nt * 2],     O[nt], 0, 0, 0);
                O[nt] = __builtin_amdgcn_mfma_f32_32x32x16_f16(pf1, vv[nt * 2 + 1], O[nt], 0, 0, 0);
            }
            __builtin_amdgcn_wave_barrier();
            #pragma unroll
            for (int t = 0; t < 8; ++t) kf[t] = kfn[t];
        }
    }
    // ---- merge the two waves' partial (m, l, O) ----
    if (shalf == 0) { mlLd[srow][w * 2] = m_run; mlLd[srow][w * 2 + 1] = l_run; }
    __syncthreads();
    if (tid < 32) {
        float m0 = mlLd[tid][0], l0 = mlLd[tid][1];
        float m1 = mlLd[tid][2], l1 = mlLd[tid][3];
        float ms = fmaxf(m0, m1);
        float f0 = __expf(m0 - ms), f1 = __expf(m1 - ms);
        float lt = f0 * l0 + f1 * l1;
        int flat = flatLd[tid];
        float hw = (flat >= 0) ? head_w[flat] : 0.f;
        facLd[tid][0] = f1;
        facLd[tid][1] = hw / lt;
        facLd[tid][2] = f0;
    }
    __syncthreads();
    if (w == 1) {
        #pragma unroll
        for (int nt = 0; nt < 4; ++nt) {
            int col = nt * 32 + l32;
            #pragma unroll
            for (int reg = 0; reg < 16; ++reg) {
                int row = (reg & 3) + 8 * (reg >> 2) + 4 * g;
                Obuf[row][col] = O[nt][reg] * facLd[row][0];
            }
        }
    }
    __syncthreads();
    if (w == 0) {
        #pragma unroll
        for (int nt = 0; nt < 4; ++nt) {
            int col = nt * 32 + l32;
            #pragma unroll
            for (int reg = 0; reg < 16; ++reg) {
                int row = (reg & 3) + 8 * (reg >> 2) + 4 * g;
                int flat = flatLd[row];
                if (flat >= 0) {
                    float val = (O[nt][reg] * facLd[row][2] + Obuf[row][col]) * facLd[row][1];
                    ao[(size_t)flat * D + col] = (_Float16)val;
                }
            }
        }
    }
}

// ---------------- output projection: 128-row m-tiles, B staged once per k-step and
// shared by two 64-row A streams. Grid (16,8); panel-sharers 16 apart (16%8==0) ----
__global__ __launch_bounds__(256) void out_mfma(
    const _Float16* __restrict__ A, const _Float16* __restrict__ Bt,
    float* __restrict__ C)
{
    int n0 = blockIdx.x * 64, m0 = blockIdx.y * 128;
    int tid = threadIdx.x, wave = tid >> 6, lane = tid & 63;
    int wm = wave >> 1, wn = wave & 1;
    int l32 = lane & 31, g = lane >> 5;

    __shared__ _Float16 Bs[2][64 * 64];

    const _Float16* aptr0 = A + (size_t)(m0 + wm * 32 + l32) * 1024;
    const _Float16* aptr1 = A + (size_t)(m0 + 64 + wm * 32 + l32) * 1024;

    auto stageB = [&](int buf, int k0) {
        #pragma unroll
        for (int it = 0; it < 2; ++it) {
            int f = it * 256 + tid;
            int row = f >> 3, c = f & 7;
            int sc = c ^ (row & 7);
            GLOAD_LDS16(Bt + (size_t)(n0 + row) * 1024 + k0 + sc * 8, &Bs[buf][f * 8]);
        }
    };

    floatx16 acc0 = {}, acc1 = {};
    int brow = wn * 32 + l32;
    half8 a_cur[2][4], a_nxt[2][4];
    #pragma unroll
    for (int ks = 0; ks < 4; ++ks) {
        a_cur[0][ks] = *(const half8*)(aptr0 + ks * 16 + g * 8);
        a_cur[1][ks] = *(const half8*)(aptr1 + ks * 16 + g * 8);
    }

    auto compute = [&](int buf, half8 a[2][4]) {
        #pragma unroll
        for (int ks = 0; ks < 4; ++ks) {
            int wchunk = ks * 2 + g;
            half8 bf = *(const half8*)&Bs[buf][brow * 64 + (wchunk ^ (brow & 7)) * 8];
            acc0 = __builtin_amdgcn_mfma_f32_32x32x16_f16(a[0][ks], bf, acc0, 0, 0, 0);
            acc1 = __builtin_amdgcn_mfma_f32_32x32x16_f16(a[1][ks], bf, acc1, 0, 0, 0);
        }
    };

    stageB(0, 0);
    __syncthreads();
    int buf = 0;
    for (int k0 = 64; k0 < 1024; k0 += 64) {
        stageB(buf ^ 1, k0);
        #pragma unroll
        for (int ks = 0; ks < 4; ++ks) {
            a_nxt[0][ks] = *(const half8*)(aptr0 + k0 + ks * 16 + g * 8);
            a_nxt[1][ks] = *(const half8*)(aptr1 + k0 + ks * 16 + g * 8);
        }
        compute(buf, a_cur);
        __syncthreads();
        buf ^= 1;
        #pragma unroll
        for (int ks = 0; ks < 4; ++ks) {
            a_cur[0][ks] = a_nxt[0][ks];
            a_cur[1][ks] = a_nxt[1][ks];
        }
    }
    compute(buf, a_cur);

    int col = n0 + wn * 32 + l32;
    #pragma unroll
    for (int reg = 0; reg < 16; ++reg) {
        int rbase = wm * 32 + (reg & 3) + 8 * (reg >> 2) + 4 * g;
        C[(size_t)(m0 + rbase) * 1024 + col]      = acc0[reg];
        C[(size_t)(m0 + 64 + rbase) * 1024 + col] = acc1[reg];
    }
}

extern "C" void kernel_launch(void* const* d_in, const int* in_sizes, int n_in,
                              void* d_out, int out_size, void* d_ws, size_t ws_size,
                              hipStream_t stream)
{
    const float* x  = (const float*)d_in[0];
    const float* Wq = (const float*)d_in[1];
    const float* Wk = (const float*)d_in[2];
    const float* Wv = (const float*)d_in[3];
    const float* Wr = (const float*)d_in[4];
    const float* Wo = (const float*)d_in[5];
    const int* head_counts = (const int*)d_in[6];
    float* out = (float*)d_out;

    float* head_w = (float*)d_ws;                 // SK
    float* pbuf   = head_w + SK;                  // S*32
    float* entz   = pbuf + S * 32;                // S*2
    int* head_idx = (int*)(entz + S * 2);         // SK
    int* order    = head_idx + SK;                // H*MAXL
    int* hlen     = order + H * MAXL;             // 32 (pad 64)
    _Float16* xh   = (_Float16*)(hlen + 64);      // S*E
    _Float16* aoh  = xh + (size_t)S * E;          // SK*D
    _Float16* Wqkt = aoh + (size_t)SK * D;        // 3*HD*E
    _Float16* Wot  = Wqkt + (size_t)3 * HD * E;   // 1024*1024
    _Float16* qh   = Wot + (size_t)1024 * 1024;   // CAP*D
    _Float16* kh   = qh + (size_t)CAP * D;        // CAP*D
    _Float16* vT   = kh + (size_t)CAP * D;        // CAP*D
    float2* tab    = (float2*)(vT + (size_t)CAP * D);   // 8192*64 float2 = 4MB

    router_conv_kernel<<<NROUTERB + NCONV + NTAB, 256, 0, stream>>>(
        x, Wr, head_idx, head_w, pbuf, entz, xh, Wq, Wk, Wv, Wo, Wqkt, Wot, tab);
    scan_aux_kernel<<<33, 256, 0, stream>>>(head_idx, head_counts, order, hlen,
                                            out + (size_t)S * E, pbuf, entz,
                                            out + (size_t)S * E + H);
    qkv_mfma<<<1536, 256, 0, stream>>>(xh, Wqkt, order, hlen, head_counts, tab,
                                       qh, kh, vT);
    attn_mfma<<<H * 32, 128, 0, stream>>>(qh, kh, vT, order, hlen, head_w, aoh);
    out_mfma<<<dim3(16, 8), 256, 0, stream>>>(aoh, Wot, out);
}

// Round 14
// 206.494 us; speedup vs baseline: 1.1293x; 1.1293x over previous
//
#include <hip/hip_runtime.h>
#include <math.h>

#define S 1024
#define E 1024
#define H 32
#define KSEL 8
#define D 128
#define HD 4096      // H*D
#define SK 8192      // S*KSEL
#define MAXL 1024
#define CAP 9216     // SK + H*31 padding (per-head padded to 32)
#define ATTN_SCALE 0.08838834764831845f  // 1/sqrt(128)
#define SSTR 36
#define PSTR 40

#define NROUTERB 1024        // one block per token (4-wave cooperative)
#define NCONV 832            // 3*(8*32) + 8*8 transpose tiles (128x128)
#define NTAB 512             // rope-table builder blocks

typedef _Float16 half8 __attribute__((ext_vector_type(8)));
typedef _Float16 half4 __attribute__((ext_vector_type(4)));
typedef float floatx16 __attribute__((ext_vector_type(16)));
typedef float f4 __attribute__((ext_vector_type(4)));

// async 16B global -> LDS (lands at wave-uniform base + lane*16)
#define GLOAD_LDS16(gsrc, ldst) \
    __builtin_amdgcn_global_load_lds( \
        (const __attribute__((address_space(1))) void*)(gsrc), \
        (__attribute__((address_space(3))) void*)(ldst), 16, 0, 0)

// ---- tiled Q/K layout: element (slot, d) of a head lives at
//   (hb + (slot&~31))*D + ((d>>3)*32 + (slot&31))*8 + (d&7)
// ---- tiled V layout: element (col, slot) at
//   (hb + (slot&~31))*D + (((slot&31)>>3)*128 + col)*8 + (slot&7)
// NOTE (round-8): device-scope fences / acquire-polling inside a BW-bound dispatch
// collapse its bandwidth 6x on gfx950 — keep scan as its own launch.
// NOTE (round-9): every global store needs exactly one owner (Wot race => absmax 20x).
// NOTE (round-10/11): XCD = linear_block_id % 8. Blocks sharing an operand panel must
// be ≡ mod 8 (same XCD L2): qkv dim3(96,16) ✓; attn h=bid&31 ✓ (+7us).
// NOTE (round-13): do NOT cluster panel-sharers consecutively within an XCD — traffic
// drops but concurrent-HBM-stream count drops more (33->46us). Many panels in flight
// IS the bandwidth. Keep (96,16).

// wave-parallel per-head prefix: 1 coalesced load + 5 shfl (vs 31 serial loads).
__device__ __forceinline__ void head_prefix(const int* __restrict__ hlen, int h,
                                            int lane, int& len, int& hb, int& lenp)
{
    int hl = (lane < 32) ? hlen[lane] : 0;
    int hp = (hl + 31) & ~31;
    int pref = hp;
    #pragma unroll
    for (int off = 1; off < 32; off <<= 1) {
        int t = __shfl_up(pref, off, 64);
        if (lane >= off) pref += t;
    }
    int excl = pref - hp;
    hb   = __shfl(excl, h, 64);
    len  = __shfl(hl, h, 64);
    lenp = (len + 31) & ~31;
}

// ---------------- merged: router (blocks 0..1023, one token per block, 4-wave E-split)
// + weight transpose/convert (HBM-bound) + rope table — disjoint pipes, one dispatch.
__global__ __launch_bounds__(256) void router_conv_kernel(
    const float* __restrict__ x, const float* __restrict__ Wr,
    int* __restrict__ head_idx, float* __restrict__ head_w,
    float* __restrict__ pbuf, float* __restrict__ entz,
    _Float16* __restrict__ xh,
    const float* __restrict__ Wq, const float* __restrict__ Wk,
    const float* __restrict__ Wv, const float* __restrict__ Wo,
    _Float16* __restrict__ Wqkt, _Float16* __restrict__ Wot,
    float2* __restrict__ tab)
{
    int bid = blockIdx.x, tid = threadIdx.x;
    __shared__ __align__(16) char smem[128 * 128 * 2];   // union: conv tile / router partials
    if (bid >= NROUTERB + NCONV) {
        // ---- rope table: tab[p*64+d2] = {cos, sin}(p * 10000^(-d2/64)) ----
        int base = (bid - NROUTERB - NCONV) * 1024;
        #pragma unroll
        for (int j = 0; j < 4; ++j) {
            int idx = base + j * 256 + tid;
            int p = idx >> 6, d2 = idx & 63;
            float inv = exp2f((float)d2 * -0.20762050f);
            float ang = (float)p * inv;
            float sn, cs;
            sincosf(ang, &sn, &cs);
            tab[idx] = make_float2(cs, sn);
        }
        return;
    }
    if (bid >= NROUTERB) {
        // ---- 128x128 weight transpose+convert (single owner per output chunk) ----
        _Float16* tl = (_Float16*)smem;
        int cb = bid - NROUTERB;
        int z, rem;
        if (cb < 768) { z = cb >> 8; rem = cb & 255; }
        else          { z = 3;       rem = cb - 768; }
        const float* W = (z == 0) ? Wq : (z == 1) ? Wk : (z == 2) ? Wv : Wo;
        _Float16* T = (z < 3) ? (Wqkt + (size_t)z * HD * E) : Wot;
        int C = (z < 3) ? HD : 1024;
        int nc = C >> 7;
        int c0 = (rem % nc) * 128;
        int r0 = (rem / nc) * 128;
        #pragma unroll
        for (int p = 0; p < 16; ++p) {
            int idx = p * 256 + tid;
            int rr = idx >> 5, cg = (idx & 31) * 4;
            f4 v = *(const f4*)&W[(size_t)(r0 + rr) * C + c0 + cg];
            half4 o;
            o.x = (_Float16)v.x; o.y = (_Float16)v.y;
            o.z = (_Float16)v.z; o.w = (_Float16)v.w;
            int sc = cg ^ (((rr >> 3) & 7) << 2);
            *(half4*)&tl[rr * 128 + sc] = o;
        }
        __syncthreads();
        #pragma unroll
        for (int p = 0; p < 8; ++p) {
            int chunk = p * 256 + tid;
            int cc = chunk >> 4, ch = chunk & 15;
            int cidx = cc ^ ((ch & 7) << 2);
            half8 o;
            #pragma unroll
            for (int j = 0; j < 8; ++j)
                o[j] = tl[(ch * 8 + j) * 128 + cidx];
            *(half8*)&T[(size_t)(c0 + cc) * 1024 + r0 + ch * 8] = o;
        }
        return;
    }
    // ---- router: ONE token per block; 4 waves split E into 8x128 segments ----
    int s = bid;
    int w = tid >> 6, lane = tid & 63;
    int h = lane & 31;
    int seg = w * 2 + (lane >> 5);          // 0..7
    float* partial = (float*)smem;          // [4][32]
    const float* xr = x + (size_t)s * E + seg * 128;
    const float* wr = Wr + (size_t)(seg * 128) * H + h;
    float a0 = 0.f, a1 = 0.f, a2 = 0.f, a3 = 0.f;
    #pragma unroll 4
    for (int e = 0; e < 128; e += 4) {
        a0 += xr[e]     * wr[e * H];
        a1 += xr[e + 1] * wr[(e + 1) * H];
        a2 += xr[e + 2] * wr[(e + 2) * H];
        a3 += xr[e + 3] * wr[(e + 3) * H];
    }
    float acc = (a0 + a1) + (a2 + a3);
    acc += __shfl_xor(acc, 32, 64);         // combine the wave's two segments
    if (lane < 32) partial[w * 32 + h] = acc;
    __syncthreads();
    float logit = partial[h] + partial[32 + h] + partial[64 + h] + partial[96 + h];
    if (w == 0) {
        float m = logit;
        #pragma unroll
        for (int off = 16; off; off >>= 1) m = fmaxf(m, __shfl_xor(m, off, 64));
        float ex = expf(logit - m);
        float Z = ex;
        #pragma unroll
        for (int off = 16; off; off >>= 1) Z += __shfl_xor(Z, off, 64);
        float p = ex / Z;
        float es = p * logf(p + 1e-8f);
        #pragma unroll
        for (int off = 16; off; off >>= 1) es += __shfl_xor(es, off, 64);
        float lse = m + logf(Z);
        float lv = logit;
        float tv[KSEL]; int ti[KSEL];
        #pragma unroll
        for (int j = 0; j < KSEL; ++j) {
            float bv = lv; int bi = h;
            #pragma unroll
            for (int off = 16; off; off >>= 1) {
                float ov = __shfl_xor(bv, off, 64);
                int oi = __shfl_xor(bi, off, 64);
                if (ov > bv || (ov == bv && oi < bi)) { bv = ov; bi = oi; }
            }
            tv[j] = bv; ti[j] = bi;
            if (h == bi) lv = -INFINITY;
        }
        float Z2 = 0.f;
        #pragma unroll
        for (int j = 0; j < KSEL; ++j) Z2 += expf(tv[j] - tv[0]);
        if (lane < 32) pbuf[s * 32 + lane] = p;
        if (lane == 0) {
            entz[s * 2]     = es;
            entz[s * 2 + 1] = lse * lse;
            #pragma unroll
            for (int j = 0; j < KSEL; ++j) {
                head_idx[s * KSEL + j] = ti[j];
                head_w[s * KSEL + j]   = expf(tv[j] - tv[0]) / Z2;
            }
        }
    }
    // fused x -> fp16: 256 threads x 4 elements, coalesced
    {
        int e = tid * 4;
        f4 v = *(const f4*)&x[(size_t)s * E + e];
        half4 o;
        o.x = (_Float16)v.x; o.y = (_Float16)v.y; o.z = (_Float16)v.z; o.w = (_Float16)v.w;
        *(half4*)&xh[(size_t)s * E + e] = o;
    }
}

// ---------------- scan (blocks 0..31) + aux (block 32): separate launch ----------------
__global__ __launch_bounds__(256) void scan_aux_kernel(
    const int* __restrict__ head_idx, const int* __restrict__ head_counts,
    int* __restrict__ order, int* __restrict__ hlen, float* __restrict__ out_counts,
    const float* __restrict__ pbuf, const float* __restrict__ entz,
    float* __restrict__ out_aux)
{
    int bid = blockIdx.x, tid = threadIdx.x;
    if (bid == H) {
        int hh = tid & 31, grp = tid >> 5;
        __shared__ float red[256], red2[256];
        __shared__ float psum[32];
        __shared__ int hist[32];
        if (tid < 32) hist[tid] = 0;
        float ps = 0.f;
        for (int s = grp; s < S; s += 8) ps += pbuf[s * 32 + hh];
        red[tid] = ps;
        float es = 0.f, zs = 0.f;
        for (int s = tid; s < S; s += 256) { es += entz[s * 2]; zs += entz[s * 2 + 1]; }
        red2[tid] = es;
        __syncthreads();
        if (grp == 0) {
            float v = 0.f;
            #pragma unroll
            for (int j = 0; j < 8; ++j) v += red[j * 32 + hh];
            psum[hh] = v;
        }
        __syncthreads();
        red[tid] = zs;
        for (int s = tid; s < S; s += 256)
            atomicAdd(&hist[head_idx[s * KSEL]], 1);
        __syncthreads();
        for (int stp = 128; stp; stp >>= 1) {
            if (tid < stp) { red[tid] += red[tid + stp]; red2[tid] += red2[tid + stp]; }
            __syncthreads();
        }
        if (tid == 0) {
            float bal = 0.f;
            for (int j = 0; j < H; ++j)
                bal += ((float)hist[j] / (float)S) * (psum[j] / (float)S);
            bal *= (float)H;
            float ent_loss = red2[0] / (float)S;
            float z = red[0] / (float)S * 0.01f;
            out_aux[0] = 0.01f * bal + 0.01f * ent_loss + z;
        }
        return;
    }
    int h = bid;
    int wave = tid >> 6, lane = tid & 63;
    __shared__ int wtot[4][4];
    int base = 0;
    int hc = head_counts[h];
    int v0 = head_idx[tid],       v1 = head_idx[256 + tid];
    int v2 = head_idx[512 + tid], v3 = head_idx[768 + tid];
    unsigned long long lt = (1ull << lane) - 1ull;
    for (int c0 = 0; c0 < SK; c0 += 1024) {
        int n0 = 0, n1 = 0, n2 = 0, n3 = 0;
        if (c0 + 1024 < SK) {
            n0 = head_idx[c0 + 1024 + tid]; n1 = head_idx[c0 + 1280 + tid];
            n2 = head_idx[c0 + 1536 + tid]; n3 = head_idx[c0 + 1792 + tid];
        }
        bool p0 = (v0 == h), p1 = (v1 == h), p2 = (v2 == h), p3 = (v3 == h);
        unsigned long long m0 = __ballot(p0), m1 = __ballot(p1);
        unsigned long long m2 = __ballot(p2), m3 = __ballot(p3);
        int w0 = __popcll(m0 & lt), w1 = __popcll(m1 & lt);
        int w2 = __popcll(m2 & lt), w3 = __popcll(m3 & lt);
        if (lane == 0) {
            wtot[0][wave] = __popcll(m0); wtot[1][wave] = __popcll(m1);
            wtot[2][wave] = __popcll(m2); wtot[3][wave] = __popcll(m3);
        }
        __syncthreads();
        int pw[4], T[4];
        #pragma unroll
        for (int i = 0; i < 4; ++i) {
            int pre = 0, tot = 0;
            #pragma unroll
            for (int w = 0; w < 4; ++w) {
                int tv = wtot[i][w];
                if (w < wave) pre += tv;
                tot += tv;
            }
            pw[i] = pre; T[i] = tot;
        }
        if (p0) order[h * MAXL + base + pw[0] + w0] = c0 + tid;
        if (p1) order[h * MAXL + base + T[0] + pw[1] + w1] = c0 + 256 + tid;
        if (p2) order[h * MAXL + base + T[0] + T[1] + pw[2] + w2] = c0 + 512 + tid;
        if (p3) order[h * MAXL + base + T[0] + T[1] + T[2] + pw[3] + w3] = c0 + 768 + tid;
        base += T[0] + T[1] + T[2] + T[3];
        __syncthreads();
        v0 = n0; v1 = n1; v2 = n2; v3 = n3;
    }
    if (tid == 0) {
        hlen[h] = base;
        out_counts[h] = (float)(hc + base);
    }
}

// ---------------- gathered QKV projection: B-only LDS dbuf, A direct-to-reg + fused RoPE
// Grid dim3(96,16): panel-sharers are 96 apart in linear id (96%8==0 -> same XCD L2),
// and 96 panels concurrently in flight keep HBM streams saturated.
__global__ __launch_bounds__(256) void qkv_mfma(
    const _Float16* __restrict__ xh, const _Float16* __restrict__ Wt,
    const int* __restrict__ order, const int* __restrict__ hlen,
    const int* __restrict__ head_counts, const float2* __restrict__ tab,
    _Float16* __restrict__ qh, _Float16* __restrict__ kh, _Float16* __restrict__ vT)
{
    int xid = blockIdx.x;
    int qkv = xid >> 5, h = xid & 31;
    int rt = blockIdx.y;
    int tid = threadIdx.x, wave = tid >> 6, lane = tid & 63;
    int len, hb, lenp;
    head_prefix(hlen, h, lane, len, hb, lenp);
    int row0 = rt * 64;
    if (row0 >= len) return;
    int wm = wave >> 1, wn = wave & 1;
    int l32 = lane & 31, g = lane >> 5;

    __shared__ _Float16 Bs[2][128 * 64];

    int arow_g = row0 + wm * 32 + l32;
    int tok = (arow_g < len) ? (order[h * MAXL + arow_g] >> 3) : 0;
    const _Float16* aptr = xh + (size_t)tok * E;
    const _Float16* Wb = Wt + (size_t)((qkv * H + h) * D) * E;

    auto stageB = [&](int buf, int k0) {
        #pragma unroll
        for (int it = 0; it < 4; ++it) {
            int f = it * 256 + tid;
            int row = f >> 3, c = f & 7;
            int sc = c ^ (row & 7);
            const _Float16* src = Wb + (size_t)row * E + k0 + sc * 8;
            GLOAD_LDS16(src, &Bs[buf][f * 8]);
        }
    };

    floatx16 acc[2] = {};
    half8 a_cur[4], a_nxt[4];
    #pragma unroll
    for (int ks = 0; ks < 4; ++ks)
        a_cur[ks] = *(const half8*)(aptr + ks * 16 + g * 8);

    auto compute = [&](int buf, half8* a) {
        #pragma unroll
        for (int ks = 0; ks < 4; ++ks) {
            int wchunk = ks * 2 + g;
            #pragma unroll
            for (int nf = 0; nf < 2; ++nf) {
                int brow = wn * 64 + nf * 32 + l32;
                half8 bf = *(const half8*)&Bs[buf][brow * 64 + (wchunk ^ (brow & 7)) * 8];
                acc[nf] = __builtin_amdgcn_mfma_f32_32x32x16_f16(a[ks], bf, acc[nf], 0, 0, 0);
            }
        }
    };

    stageB(0, 0);
    __syncthreads();
    int buf = 0;
    for (int k0 = 64; k0 < E; k0 += 64) {
        stageB(buf ^ 1, k0);
        #pragma unroll
        for (int ks = 0; ks < 4; ++ks)
            a_nxt[ks] = *(const half8*)(aptr + k0 + ks * 16 + g * 8);
        compute(buf, a_cur);
        __syncthreads();
        buf ^= 1;
        #pragma unroll
        for (int ks = 0; ks < 4; ++ks) a_cur[ks] = a_nxt[ks];
    }
    compute(buf, a_cur);

    if (qkv < 2) {
        // fused RoPE -> TILED write: (slot,d) -> (hb+(slot&~31))*D + ((d>>3)*32+(slot&31))*8 + (d&7)
        _Float16* dst = (qkv == 0) ? qh : kh;
        float* scr = (float*)&Bs[0][0];
        __syncthreads();
        #pragma unroll
        for (int nf = 0; nf < 2; ++nf) {
            int col = wn * 64 + nf * 32 + l32;
            #pragma unroll
            for (int reg = 0; reg < 16; ++reg) {
                int rl = wm * 32 + (reg & 3) + 8 * (reg >> 2) + 4 * g;
                scr[rl * 128 + col] = acc[nf][reg];
            }
        }
        __syncthreads();
        int hc = head_counts[h];
        #pragma unroll
        for (int pass = 0; pass < 16; ++pass) {
            int idx = pass * 256 + tid;
            int r = idx >> 6, d2 = idx & 63;
            int slot = row0 + r;
            if (slot < len) {
                float v1 = scr[r * 128 + d2], v2 = scr[r * 128 + 64 + d2];
                int p = slot + hc;
                p = p < 0 ? 0 : (p > 8191 ? 8191 : p);
                float2 tt = tab[p * 64 + d2];
                size_t tb = (size_t)(hb + (slot & ~31)) * D;
                int sl5 = slot & 31;
                int c0 = d2 >> 3, e0 = d2 & 7;
                dst[tb + (size_t)(c0 * 32 + sl5) * 8 + e0]       = (_Float16)(v1 * tt.x - v2 * tt.y);
                dst[tb + (size_t)((c0 + 8) * 32 + sl5) * 8 + e0] = (_Float16)(v2 * tt.x + v1 * tt.y);
            }
        }
    } else {
        // TILED V write: (col,slot) -> (hb+(slot&~31))*D + (((slot&31)>>3)*128+col)*8 + (slot&7)
        #pragma unroll
        for (int nf = 0; nf < 2; ++nf) {
            int col = wn * 64 + nf * 32 + l32;
            #pragma unroll
            for (int q4 = 0; q4 < 4; ++q4) {
                int slot0 = row0 + wm * 32 + 8 * q4 + 4 * g;
                size_t tb = (size_t)(hb + (slot0 & ~31)) * D;
                int sc = (slot0 & 31) >> 3;
                _Float16* vp = vT + tb + (size_t)(sc * 128 + col) * 8 + (slot0 & 7);
                if (slot0 + 3 < len) {
                    half4 o;
                    o.x = (_Float16)acc[nf][q4 * 4 + 0];
                    o.y = (_Float16)acc[nf][q4 * 4 + 1];
                    o.z = (_Float16)acc[nf][q4 * 4 + 2];
                    o.w = (_Float16)acc[nf][q4 * 4 + 3];
                    *(half4*)vp = o;
                } else {
                    #pragma unroll
                    for (int r2 = 0; r2 < 4; ++r2) {
                        int sl = slot0 + r2;
                        if (sl < len) vp[r2] = (_Float16)acc[nf][q4 * 4 + r2];
                        else if (sl < lenp) vp[r2] = (_Float16)0.f;   // keep pad NaN-free
                    }
                }
            }
        }
    }
}

// ---------------- per-head causal flash attention: tiled dense loads.
// h = bid&31 (XCD = h%8: per-head K/V stays in one XCD's L2), qt = 31-(bid>>5).
__global__ __launch_bounds__(128) void attn_mfma(
    const _Float16* __restrict__ qh, const _Float16* __restrict__ kh,
    const _Float16* __restrict__ vT,
    const int* __restrict__ order, const int* __restrict__ hlen,
    const float* __restrict__ head_w, _Float16* __restrict__ ao)
{
    int h = blockIdx.x & 31;
    int qt = 31 - (int)(blockIdx.x >> 5);
    int tid = threadIdx.x;
    int w = tid >> 6, lane = tid & 63;
    int len, hb, lenp;
    head_prefix(hlen, h, lane, len, hb, lenp);
    int row0 = qt * 32;
    if (row0 >= len) return;
    int l32 = lane & 31, g = lane >> 5;
    int srow = lane >> 1, shalf = lane & 1;

    __shared__ float Sld[2][32 * SSTR];
    __shared__ _Float16 Pld[2][32 * PSTR];
    __shared__ float alphaLd[2][32];
    __shared__ float mlLd[32][4];     // m0,l0,m1,l1
    __shared__ float facLd[32][3];    // f1, hw/l*, f0
    __shared__ int flatLd[32];
    __shared__ float Obuf[32][128];

    if (tid < 32) {
        int r = row0 + tid;
        flatLd[tid] = (r < len) ? order[h * MAXL + r] : -1;
    }

    // dense tiled Q load: 1KB contiguous per wave-chunk
    const _Float16* qtile = qh + (size_t)(hb + row0) * D;
    half8 qf[8];
    #pragma unroll
    for (int t = 0; t < 8; ++t)
        qf[t] = *(const half8*)(qtile + (size_t)((t * 2 + g) * 32 + l32) * 8);

    floatx16 O[4] = {};
    float m_run = -INFINITY, l_run = 0.f;

    if (w <= qt) {
        half8 kf[8], kfn[8], vv[8];
        {
            const _Float16* ktile = kh + (size_t)(hb + w * 32) * D;
            #pragma unroll
            for (int t = 0; t < 8; ++t)
                kf[t] = *(const half8*)(ktile + (size_t)((t * 2 + g) * 32 + l32) * 8);
        }
        for (int kt = w; kt <= qt; kt += 2) {
            int col0 = kt * 32;
            floatx16 Sc = {};
            #pragma unroll
            for (int t = 0; t < 8; ++t)
                Sc = __builtin_amdgcn_mfma_f32_32x32x16_f16(qf[t], kf[t], Sc, 0, 0, 0);
            // dense tiled V load for this kt tile
            {
                const _Float16* vtile = vT + (size_t)(hb + col0) * D;
                #pragma unroll
                for (int nt = 0; nt < 4; ++nt) {
                    vv[nt * 2]     = *(const half8*)(vtile + (size_t)(g * 128 + nt * 32 + l32) * 8);
                    vv[nt * 2 + 1] = *(const half8*)(vtile + (size_t)((2 + g) * 128 + nt * 32 + l32) * 8);
                }
            }
            if (kt + 2 <= qt) {
                const _Float16* ktile = kh + (size_t)(hb + col0 + 64) * D;
                #pragma unroll
                for (int t = 0; t < 8; ++t)
                    kfn[t] = *(const half8*)(ktile + (size_t)((t * 2 + g) * 32 + l32) * 8);
            }
            bool diag = (kt == qt);
            #pragma unroll
            for (int reg = 0; reg < 16; ++reg) {
                int row = (reg & 3) + 8 * (reg >> 2) + 4 * g;
                float s = Sc[reg] * ATTN_SCALE;
                if (diag && l32 > row) s = -1e30f;
                Sld[w][row * SSTR + l32] = s;
            }
            __builtin_amdgcn_wave_barrier();
            const float* sp = &Sld[w][srow * SSTR + shalf * 16];
            float va[16];
            *(f4*)(va)      = *(const f4*)(sp);
            *(f4*)(va + 4)  = *(const f4*)(sp + 4);
            *(f4*)(va + 8)  = *(const f4*)(sp + 8);
            *(f4*)(va + 12) = *(const f4*)(sp + 12);
            float mt_ = va[0];
            #pragma unroll
            for (int j = 1; j < 16; ++j) mt_ = fmaxf(mt_, va[j]);
            mt_ = fmaxf(mt_, __shfl_xor(mt_, 1, 64));
            float m_new = fmaxf(m_run, mt_);
            float alpha = __expf(m_run - m_new);
            float p[16], tsum = 0.f;
            #pragma unroll
            for (int j = 0; j < 16; ++j) { p[j] = __expf(va[j] - m_new); tsum += p[j]; }
            tsum += __shfl_xor(tsum, 1, 64);
            l_run = l_run * alpha + tsum;
            m_run = m_new;
            half8 ph0, ph1;
            #pragma unroll
            for (int j = 0; j < 8; ++j) { ph0[j] = (_Float16)p[j]; ph1[j] = (_Float16)p[j + 8]; }
            *(half8*)&Pld[w][srow * PSTR + shalf * 16]     = ph0;
            *(half8*)&Pld[w][srow * PSTR + shalf * 16 + 8] = ph1;
            if (shalf == 0) alphaLd[w][srow] = alpha;
            __builtin_amdgcn_wave_barrier();
            f4 al[4];
            #pragma unroll
            for (int qq = 0; qq < 4; ++qq) al[qq] = *(const f4*)&alphaLd[w][4 * g + 8 * qq];
            #pragma unroll
            for (int reg = 0; reg < 16; ++reg) {
                float av = al[reg >> 2][reg & 3];
                O[0][reg] *= av; O[1][reg] *= av; O[2][reg] *= av; O[3][reg] *= av;
            }
            half8 pf0 = *(const half8*)&Pld[w][l32 * PSTR + g * 8];
            half8 pf1 = *(const half8*)&Pld[w][l32 * PSTR + 16 + g * 8];
            #pragma unroll
            for (int nt = 0; nt < 4; ++nt) {
                O[nt] = __builtin_amdgcn_mfma_f32_32x32x16_f16(pf0, vv[nt * 2],     O[nt], 0, 0, 0);
                O[nt] = __builtin_amdgcn_mfma_f32_32x32x16_f16(pf1, vv[nt * 2 + 1], O[nt], 0, 0, 0);
            }
            __builtin_amdgcn_wave_barrier();
            #pragma unroll
            for (int t = 0; t < 8; ++t) kf[t] = kfn[t];
        }
    }
    // ---- merge the two waves' partial (m, l, O) ----
    if (shalf == 0) { mlLd[srow][w * 2] = m_run; mlLd[srow][w * 2 + 1] = l_run; }
    __syncthreads();
    if (tid < 32) {
        float m0 = mlLd[tid][0], l0 = mlLd[tid][1];
        float m1 = mlLd[tid][2], l1 = mlLd[tid][3];
        float ms = fmaxf(m0, m1);
        float f0 = __expf(m0 - ms), f1 = __expf(m1 - ms);
        float lt = f0 * l0 + f1 * l1;
        int flat = flatLd[tid];
        float hw = (flat >= 0) ? head_w[flat] : 0.f;
        facLd[tid][0] = f1;
        facLd[tid][1] = hw / lt;
        facLd[tid][2] = f0;
    }
    __syncthreads();
    if (w == 1) {
        #pragma unroll
        for (int nt = 0; nt < 4; ++nt) {
            int col = nt * 32 + l32;
            #pragma unroll
            for (int reg = 0; reg < 16; ++reg) {
                int row = (reg & 3) + 8 * (reg >> 2) + 4 * g;
                Obuf[row][col] = O[nt][reg] * facLd[row][0];
            }
        }
    }
    __syncthreads();
    if (w == 0) {
        #pragma unroll
        for (int nt = 0; nt < 4; ++nt) {
            int col = nt * 32 + l32;
            #pragma unroll
            for (int reg = 0; reg < 16; ++reg) {
                int row = (reg & 3) + 8 * (reg >> 2) + 4 * g;
                int flat = flatLd[row];
                if (flat >= 0) {
                    float val = (O[nt][reg] * facLd[row][2] + Obuf[row][col]) * facLd[row][1];
                    ao[(size_t)flat * D + col] = (_Float16)val;
                }
            }
        }
    }
}

// ---------------- output projection: B-only LDS dbuf MFMA GEMM, A direct-to-reg ----------------
__global__ __launch_bounds__(256) void out_mfma(
    const _Float16* __restrict__ A, const _Float16* __restrict__ Bt,
    float* __restrict__ C)
{
    int n0 = blockIdx.x * 64, m0 = blockIdx.y * 64;
    int tid = threadIdx.x, wave = tid >> 6, lane = tid & 63;
    int wm = wave >> 1, wn = wave & 1;
    int l32 = lane & 31, g = lane >> 5;

    __shared__ _Float16 Bs[2][64 * 64];

    const _Float16* aptr = A + (size_t)(m0 + wm * 32 + l32) * 1024;

    auto stageB = [&](int buf, int k0) {
        #pragma unroll
        for (int it = 0; it < 2; ++it) {
            int f = it * 256 + tid;
            int row = f >> 3, c = f & 7;
            int sc = c ^ (row & 7);
            GLOAD_LDS16(Bt + (size_t)(n0 + row) * 1024 + k0 + sc * 8, &Bs[buf][f * 8]);
        }
    };

    floatx16 acc = {};
    int brow = wn * 32 + l32;
    half8 a_cur[4], a_nxt[4];
    #pragma unroll
    for (int ks = 0; ks < 4; ++ks)
        a_cur[ks] = *(const half8*)(aptr + ks * 16 + g * 8);

    auto compute = [&](int buf, half8* a) {
        #pragma unroll
        for (int ks = 0; ks < 4; ++ks) {
            int wchunk = ks * 2 + g;
            half8 bf = *(const half8*)&Bs[buf][brow * 64 + (wchunk ^ (brow & 7)) * 8];
            acc = __builtin_amdgcn_mfma_f32_32x32x16_f16(a[ks], bf, acc, 0, 0, 0);
        }
    };

    stageB(0, 0);
    __syncthreads();
    int buf = 0;
    for (int k0 = 64; k0 < 1024; k0 += 64) {
        stageB(buf ^ 1, k0);
        #pragma unroll
        for (int ks = 0; ks < 4; ++ks)
            a_nxt[ks] = *(const half8*)(aptr + k0 + ks * 16 + g * 8);
        compute(buf, a_cur);
        __syncthreads();
        buf ^= 1;
        #pragma unroll
        for (int ks = 0; ks < 4; ++ks) a_cur[ks] = a_nxt[ks];
    }
    compute(buf, a_cur);

    int col = n0 + wn * 32 + l32;
    #pragma unroll
    for (int reg = 0; reg < 16; ++reg) {
        int row = m0 + wm * 32 + (reg & 3) + 8 * (reg >> 2) + 4 * g;
        C[(size_t)row * 1024 + col] = acc[reg];
    }
}

extern "C" void kernel_launch(void* const* d_in, const int* in_sizes, int n_in,
                              void* d_out, int out_size, void* d_ws, size_t ws_size,
                              hipStream_t stream)
{
    const float* x  = (const float*)d_in[0];
    const float* Wq = (const float*)d_in[1];
    const float* Wk = (const float*)d_in[2];
    const float* Wv = (const float*)d_in[3];
    const float* Wr = (const float*)d_in[4];
    const float* Wo = (const float*)d_in[5];
    const int* head_counts = (const int*)d_in[6];
    float* out = (float*)d_out;

    float* head_w = (float*)d_ws;                 // SK
    float* pbuf   = head_w + SK;                  // S*32
    float* entz   = pbuf + S * 32;                // S*2
    int* head_idx = (int*)(entz + S * 2);         // SK
    int* order    = head_idx + SK;                // H*MAXL
    int* hlen     = order + H * MAXL;             // 32 (pad 64)
    _Float16* xh   = (_Float16*)(hlen + 64);      // S*E
    _Float16* aoh  = xh + (size_t)S * E;          // SK*D
    _Float16* Wqkt = aoh + (size_t)SK * D;        // 3*HD*E
    _Float16* Wot  = Wqkt + (size_t)3 * HD * E;   // 1024*1024
    _Float16* qh   = Wot + (size_t)1024 * 1024;   // CAP*D
    _Float16* kh   = qh + (size_t)CAP * D;        // CAP*D
    _Float16* vT   = kh + (size_t)CAP * D;        // CAP*D
    float2* tab    = (float2*)(vT + (size_t)CAP * D);   // 8192*64 float2 = 4MB

    router_conv_kernel<<<NROUTERB + NCONV + NTAB, 256, 0, stream>>>(
        x, Wr, head_idx, head_w, pbuf, entz, xh, Wq, Wk, Wv, Wo, Wqkt, Wot, tab);
    scan_aux_kernel<<<33, 256, 0, stream>>>(head_idx, head_counts, order, hlen,
                                            out + (size_t)S * E, pbuf, entz,
                                            out + (size_t)S * E + H);
    qkv_mfma<<<dim3(96, 16), 256, 0, stream>>>(xh, Wqkt, order, hlen, head_counts, tab,
                                               qh, kh, vT);
    attn_mfma<<<H * 32, 128, 0, stream>>>(qh, kh, vT, order, hlen, head_w, aoh);
    out_mfma<<<dim3(16, 16), 256, 0, stream>>>(aoh, Wot, out);
}